// Round 2
// baseline (602.827 us; speedup 1.0000x reference)
//
#include <hip/hip_runtime.h>
#include <hip/hip_bf16.h>

#define EMB 1024
#define NH 16
#define HD 64
#define BATCH 8
#define SEQ 1024
#define ROWS (BATCH*SEQ)   // 8192

typedef unsigned short ushort_t;
typedef __attribute__((ext_vector_type(8))) short bf16x8;
typedef __attribute__((ext_vector_type(4))) float f32x4;

__device__ __forceinline__ float bf2f(ushort_t u){
    union { unsigned int i; float f; } v; v.i = ((unsigned int)u) << 16; return v.f;
}
__device__ __forceinline__ ushort_t f2bf(float f){
    unsigned int u = __float_as_uint(f);
    unsigned int r = (u + 0x7FFFu + ((u >> 16) & 1u)) >> 16;
    return (ushort_t)r;
}

// ---------------- weight transpose + convert (f32 [K][N] -> bf16 [N][K]) ----------------
__global__ __launch_bounds__(256) void transpose_w(const float* __restrict__ in,
                                                   ushort_t* __restrict__ out,
                                                   int K, int N){
    __shared__ ushort_t t[32][33];
    int tx = threadIdx.x & 31, ty = threadIdx.x >> 5;
    int bx = blockIdx.x, by = blockIdx.y;
    #pragma unroll
    for (int r = 0; r < 4; ++r)
        t[ty + r*8][tx] = f2bf(in[(size_t)(by*32 + ty + r*8) * N + bx*32 + tx]);
    __syncthreads();
    #pragma unroll
    for (int r = 0; r < 4; ++r)
        out[(size_t)(bx*32 + ty + r*8) * K + by*32 + tx] = t[tx][ty + r*8];
}

// ---------------- LayerNorm (row = 1024), f32 in -> bf16 out ----------------
__global__ __launch_bounds__(256) void ln_kernel(const float* __restrict__ xin,
                                                 const float* __restrict__ g,
                                                 const float* __restrict__ bia,
                                                 ushort_t* __restrict__ out){
    int row = blockIdx.x;
    int tid = threadIdx.x;
    const float* x = xin + (size_t)row * EMB;
    float4 f = *(const float4*)(x + tid*4);
    float v[4] = {f.x, f.y, f.z, f.w};
    float s = v[0]+v[1]+v[2]+v[3];
    float q = v[0]*v[0]+v[1]*v[1]+v[2]*v[2]+v[3]*v[3];
    #pragma unroll
    for (int o = 32; o > 0; o >>= 1){ s += __shfl_down(s, o); q += __shfl_down(q, o); }
    __shared__ float ss[4], qq[4];
    __shared__ float mu_s, sc_s;
    int wave = tid >> 6, lane = tid & 63;
    if (lane == 0){ ss[wave] = s; qq[wave] = q; }
    __syncthreads();
    if (tid == 0){
        float S = ss[0]+ss[1]+ss[2]+ss[3];
        float Q = qq[0]+qq[1]+qq[2]+qq[3];
        float mu = S * (1.0f/EMB);
        float var = Q * (1.0f/EMB) - mu*mu;
        mu_s = mu; sc_s = rsqrtf(var + 1e-5f);
    }
    __syncthreads();
    float mu = mu_s, sc = sc_s;
    float4 gu = *(const float4*)(g + tid*4);
    float4 bu = *(const float4*)(bia + tid*4);
    ushort4 o4;
    o4.x = f2bf((v[0]-mu)*sc*gu.x + bu.x);
    o4.y = f2bf((v[1]-mu)*sc*gu.y + bu.y);
    o4.z = f2bf((v[2]-mu)*sc*gu.z + bu.z);
    o4.w = f2bf((v[3]-mu)*sc*gu.w + bu.w);
    *(ushort4*)(out + (size_t)row*EMB + tid*4) = o4;
}

// ---------------- GEMM: C[M][N] = epilogue(A[M][K] @ Bt[N][K]^T) ----------------
// A, Bt are bf16. bias/resid are f32.
// MODE 0: plain -> bf16 out
// MODE 1: + bias + resid(f32) -> f32 out
// MODE 2: + bias + GELU(exact) -> bf16 out
// MODE 3: + bias + resid(f32)  -> f32 out (final)
template<int MODE>
__global__ __launch_bounds__(256) void gemm_kernel(const ushort_t* __restrict__ A,
                                                   const ushort_t* __restrict__ Bt,
                                                   const float* __restrict__ bias,
                                                   const float* __restrict__ resid,
                                                   void* __restrict__ out,
                                                   int M, int N, int K){
    __shared__ ushort_t As[128][72];
    __shared__ ushort_t Bs[128][72];
    int tid = threadIdx.x;
    int lane = tid & 63, wave = tid >> 6;
    int quad = lane >> 4, l15 = lane & 15;
    int wm = wave >> 1, wn = wave & 1;
    int m0 = blockIdx.y * 128, n0 = blockIdx.x * 128;

    f32x4 acc[4][4];
    #pragma unroll
    for (int i=0;i<4;i++)
        #pragma unroll
        for (int j=0;j<4;j++) acc[i][j] = (f32x4){0.f,0.f,0.f,0.f};

    int tr = tid >> 3;
    int tc = (tid & 7) * 8;

    for (int k0 = 0; k0 < K; k0 += 64){
        #pragma unroll
        for (int p = 0; p < 4; ++p){
            int row = tr + p*32;
            *(bf16x8*)&As[row][tc] = *(const bf16x8*)(A  + (size_t)(m0+row)*K + k0 + tc);
            *(bf16x8*)&Bs[row][tc] = *(const bf16x8*)(Bt + (size_t)(n0+row)*K + k0 + tc);
        }
        __syncthreads();
        #pragma unroll
        for (int kf = 0; kf < 2; ++kf){
            bf16x8 af[4], bfr[4];
            #pragma unroll
            for (int i=0;i<4;i++) af[i]  = *(const bf16x8*)&As[wm*64 + i*16 + l15][kf*32 + quad*8];
            #pragma unroll
            for (int j=0;j<4;j++) bfr[j] = *(const bf16x8*)&Bs[wn*64 + j*16 + l15][kf*32 + quad*8];
            #pragma unroll
            for (int i=0;i<4;i++)
                #pragma unroll
                for (int j=0;j<4;j++)
                    acc[i][j] = __builtin_amdgcn_mfma_f32_16x16x32_bf16(af[i], bfr[j], acc[i][j], 0,0,0);
        }
        __syncthreads();
    }

    #pragma unroll
    for (int i=0;i<4;i++){
        int m = m0 + wm*64 + i*16 + quad*4;
        #pragma unroll
        for (int j=0;j<4;j++){
            int n = n0 + wn*64 + j*16 + l15;
            #pragma unroll
            for (int r=0;r<4;r++){
                float v = acc[i][j][r];
                size_t idx = (size_t)(m + r)*N + n;
                if (MODE == 0){
                    ((ushort_t*)out)[idx] = f2bf(v);
                } else if (MODE == 1){
                    v += bias[n] + resid[idx];
                    ((float*)out)[idx] = v;
                } else if (MODE == 2){
                    v += bias[n];
                    v = 0.5f * v * (1.0f + erff(v * 0.70710678118654752f));
                    ((ushort_t*)out)[idx] = f2bf(v);
                } else {
                    v += bias[n] + resid[idx];
                    ((float*)out)[idx] = v;
                }
            }
        }
    }
}

// ---------------- Flash attention (causal), D=64, KV tile = 64 ----------------
__global__ __launch_bounds__(256) void attn_kernel(const ushort_t* __restrict__ qkv,
                                                   ushort_t* __restrict__ attn_out){
    __shared__ ushort_t Qs[128][72];
    __shared__ ushort_t Ks[64][72];
    __shared__ ushort_t Vts[64][72];   // V transposed: Vts[d][kv]
    __shared__ ushort_t Ps[128][72];

    int tid = threadIdx.x;
    int lane = tid & 63, wave = tid >> 6;
    int quad = lane >> 4, l15 = lane & 15;
    int qi = blockIdx.x;           // 0..7 (q tile of 128)
    int bh = blockIdx.y;           // 0..127
    int b = bh >> 4, h = bh & 15;
    size_t tb = (size_t)b * SEQ;

    int tr = tid >> 3;             // 0..31
    int tc = (tid & 7) * 8;        // 0..56

    // stage Q tile [128][64]
    #pragma unroll
    for (int p = 0; p < 4; ++p){
        int r = tr + p*32;
        size_t tok = tb + qi*128 + r;
        *(bf16x8*)&Qs[r][tc] = *(const bf16x8*)(qkv + tok*3072 + h*64 + tc);
    }

    f32x4 o_acc[2][4];
    #pragma unroll
    for (int mt=0;mt<2;mt++)
        #pragma unroll
        for (int nt=0;nt<4;nt++) o_acc[mt][nt] = (f32x4){0.f,0.f,0.f,0.f};
    float m_st[2][4], l_st[2][4];
    #pragma unroll
    for (int mt=0;mt<2;mt++)
        #pragma unroll
        for (int r=0;r<4;r++){ m_st[mt][r] = -1e30f; l_st[mt][r] = 0.f; }

    int nj = 2*qi + 2;
    for (int j = 0; j < nj; ++j){
        // stage K tile [64][64] and V transposed [64][64]
        #pragma unroll
        for (int p = 0; p < 2; ++p){
            int r = tr + p*32;
            size_t tok = tb + j*64 + r;
            *(bf16x8*)&Ks[r][tc] = *(const bf16x8*)(qkv + tok*3072 + 1024 + h*64 + tc);
            bf16x8 vv = *(const bf16x8*)(qkv + tok*3072 + 2048 + h*64 + tc);
            #pragma unroll
            for (int c = 0; c < 8; ++c) Vts[tc + c][r] = (ushort_t)vv[c];
        }
        __syncthreads();

        // S = Q @ K^T  (per wave: 32 q rows x 64 kv)
        f32x4 s_acc[2][4];
        #pragma unroll
        for (int mt=0;mt<2;mt++)
            #pragma unroll
            for (int nt=0;nt<4;nt++) s_acc[mt][nt] = (f32x4){0.f,0.f,0.f,0.f};
        #pragma unroll
        for (int kf = 0; kf < 2; ++kf){
            bf16x8 aq[2], bk[4];
            #pragma unroll
            for (int mt=0;mt<2;mt++) aq[mt] = *(const bf16x8*)&Qs[wave*32 + mt*16 + l15][kf*32 + quad*8];
            #pragma unroll
            for (int nt=0;nt<4;nt++) bk[nt] = *(const bf16x8*)&Ks[nt*16 + l15][kf*32 + quad*8];
            #pragma unroll
            for (int mt=0;mt<2;mt++)
                #pragma unroll
                for (int nt=0;nt<4;nt++)
                    s_acc[mt][nt] = __builtin_amdgcn_mfma_f32_16x16x32_bf16(aq[mt], bk[nt], s_acc[mt][nt], 0,0,0);
        }

        bool need_mask = (j >= 2*qi);
        #pragma unroll
        for (int mt=0;mt<2;mt++)
            #pragma unroll
            for (int nt=0;nt<4;nt++)
                #pragma unroll
                for (int r=0;r<4;r++){
                    float s = s_acc[mt][nt][r] * 0.125f;
                    if (need_mask){
                        int qg = qi*128 + wave*32 + mt*16 + quad*4 + r;
                        int kg = j*64 + nt*16 + l15;
                        if (kg > qg) s = -1e30f;
                    }
                    s_acc[mt][nt][r] = s;
                }

        // online softmax per q row
        #pragma unroll
        for (int mt=0;mt<2;mt++){
            #pragma unroll
            for (int r=0;r<4;r++){
                float rm = s_acc[mt][0][r];
                #pragma unroll
                for (int nt=1;nt<4;nt++) rm = fmaxf(rm, s_acc[mt][nt][r]);
                rm = fmaxf(rm, __shfl_xor(rm, 1));
                rm = fmaxf(rm, __shfl_xor(rm, 2));
                rm = fmaxf(rm, __shfl_xor(rm, 4));
                rm = fmaxf(rm, __shfl_xor(rm, 8));
                float mnew = fmaxf(m_st[mt][r], rm);
                float alpha = __expf(m_st[mt][r] - mnew);
                float rsum = 0.f;
                #pragma unroll
                for (int nt=0;nt<4;nt++){
                    float p = __expf(s_acc[mt][nt][r] - mnew);
                    s_acc[mt][nt][r] = p;
                    rsum += p;
                }
                rsum += __shfl_xor(rsum, 1);
                rsum += __shfl_xor(rsum, 2);
                rsum += __shfl_xor(rsum, 4);
                rsum += __shfl_xor(rsum, 8);
                l_st[mt][r] = l_st[mt][r]*alpha + rsum;
                m_st[mt][r] = mnew;
                #pragma unroll
                for (int nt=0;nt<4;nt++) o_acc[mt][nt][r] *= alpha;
            }
        }

        // write P (bf16) to LDS in its wave-private region
        #pragma unroll
        for (int mt=0;mt<2;mt++)
            #pragma unroll
            for (int nt=0;nt<4;nt++)
                #pragma unroll
                for (int r=0;r<4;r++)
                    Ps[wave*32 + mt*16 + quad*4 + r][nt*16 + l15] = f2bf(s_acc[mt][nt][r]);

        // O += P @ V
        #pragma unroll
        for (int kf = 0; kf < 2; ++kf){
            bf16x8 ap[2], bv[4];
            #pragma unroll
            for (int mt=0;mt<2;mt++) ap[mt] = *(const bf16x8*)&Ps[wave*32 + mt*16 + l15][kf*32 + quad*8];
            #pragma unroll
            for (int nt=0;nt<4;nt++) bv[nt] = *(const bf16x8*)&Vts[nt*16 + l15][kf*32 + quad*8];
            #pragma unroll
            for (int mt=0;mt<2;mt++)
                #pragma unroll
                for (int nt=0;nt<4;nt++)
                    o_acc[mt][nt] = __builtin_amdgcn_mfma_f32_16x16x32_bf16(ap[mt], bv[nt], o_acc[mt][nt], 0,0,0);
        }
        __syncthreads();
    }

    // epilogue: O /= l, store bf16
    #pragma unroll
    for (int mt=0;mt<2;mt++)
        #pragma unroll
        for (int r=0;r<4;r++){
            float inv = 1.0f / l_st[mt][r];
            size_t tok = tb + qi*128 + wave*32 + mt*16 + quad*4 + r;
            #pragma unroll
            for (int nt=0;nt<4;nt++)
                attn_out[tok*EMB + h*64 + nt*16 + l15] = f2bf(o_acc[mt][nt][r] * inv);
        }
}

extern "C" void kernel_launch(void* const* d_in, const int* in_sizes, int n_in,
                              void* d_out, int out_size, void* d_ws, size_t ws_size,
                              hipStream_t stream){
    const float* x      = (const float*)d_in[0];
    const float* ln1_g  = (const float*)d_in[1];
    const float* ln1_b  = (const float*)d_in[2];
    const float* wq     = (const float*)d_in[3];
    const float* wk     = (const float*)d_in[4];
    const float* wv     = (const float*)d_in[5];
    const float* w_proj = (const float*)d_in[6];
    const float* b_proj = (const float*)d_in[7];
    const float* ln2_g  = (const float*)d_in[8];
    const float* ln2_b  = (const float*)d_in[9];
    const float* w1     = (const float*)d_in[10];
    const float* b1     = (const float*)d_in[11];
    const float* w2     = (const float*)d_in[12];
    const float* b2     = (const float*)d_in[13];
    float* outp = (float*)d_out;

    char* ws = (char*)d_ws;
    size_t off = 0;
    auto alloc = [&](size_t bytes)->char*{ char* p = ws + off; off += (bytes + 255) & ~255ULL; return p; };
    ushort_t* wqkv_t = (ushort_t*)alloc((size_t)3072*1024*2);  // 6.3 MB
    ushort_t* wproj_t= (ushort_t*)alloc((size_t)1024*1024*2);  // 2 MB
    ushort_t* w1_t   = (ushort_t*)alloc((size_t)4096*1024*2);  // 8 MB
    ushort_t* w2_t   = (ushort_t*)alloc((size_t)1024*4096*2);  // 8 MB
    ushort_t* qkv    = (ushort_t*)alloc((size_t)ROWS*3072*2);  // 48 MB (reused for h2)
    ushort_t* hbuf   = (ushort_t*)alloc((size_t)ROWS*1024*2);  // 16 MB (h1, then attn)
    float*    out32  = (float*)  alloc((size_t)ROWS*1024*4);   // 32 MB
    ushort_t* mid    = (ushort_t*)alloc((size_t)ROWS*4096*2);  // 64 MB
    ushort_t* h1 = hbuf;
    ushort_t* attn = hbuf;   // h1 dead after qkv GEMM
    ushort_t* h2 = qkv;      // qkv dead after attention

    dim3 blk(256);
    transpose_w<<<dim3(32,32),  blk, 0, stream>>>(wq,     wqkv_t,               1024, 1024);
    transpose_w<<<dim3(32,32),  blk, 0, stream>>>(wk,     wqkv_t + 1024*1024,   1024, 1024);
    transpose_w<<<dim3(32,32),  blk, 0, stream>>>(wv,     wqkv_t + 2*1024*1024, 1024, 1024);
    transpose_w<<<dim3(32,32),  blk, 0, stream>>>(w_proj, wproj_t,              1024, 1024);
    transpose_w<<<dim3(128,32), blk, 0, stream>>>(w1,     w1_t,                 1024, 4096);
    transpose_w<<<dim3(32,128), blk, 0, stream>>>(w2,     w2_t,                 4096, 1024);

    ln_kernel<<<ROWS, blk, 0, stream>>>(x, ln1_g, ln1_b, h1);
    gemm_kernel<0><<<dim3(3072/128, ROWS/128), blk, 0, stream>>>(h1, wqkv_t, nullptr, nullptr, qkv, ROWS, 3072, 1024);
    attn_kernel<<<dim3(8,128), blk, 0, stream>>>(qkv, attn);
    gemm_kernel<1><<<dim3(1024/128, ROWS/128), blk, 0, stream>>>(attn, wproj_t, b_proj, x, out32, ROWS, 1024, 1024);
    ln_kernel<<<ROWS, blk, 0, stream>>>(out32, ln2_g, ln2_b, h2);
    gemm_kernel<2><<<dim3(4096/128, ROWS/128), blk, 0, stream>>>(h2, w1_t, b1, nullptr, mid, ROWS, 4096, 1024);
    gemm_kernel<3><<<dim3(1024/128, ROWS/128), blk, 0, stream>>>(mid, w2_t, b2, out32, outp, ROWS, 1024, 4096);
}

// Round 3
// 567.733 us; speedup vs baseline: 1.0618x; 1.0618x over previous
//
#include <hip/hip_runtime.h>
#include <hip/hip_bf16.h>

#define EMB 1024
#define NH 16
#define HD 64
#define BATCH 8
#define SEQ 1024
#define ROWS (BATCH*SEQ)   // 8192

typedef unsigned short ushort_t;
typedef __attribute__((ext_vector_type(8))) short bf16x8;
typedef __attribute__((ext_vector_type(4))) float f32x4;

__device__ __forceinline__ float bf2f(ushort_t u){
    union { unsigned int i; float f; } v; v.i = ((unsigned int)u) << 16; return v.f;
}
__device__ __forceinline__ ushort_t f2bf(float f){
    unsigned int u = __float_as_uint(f);
    unsigned int r = (u + 0x7FFFu + ((u >> 16) & 1u)) >> 16;
    return (ushort_t)r;
}
__device__ __forceinline__ void gload16(const ushort_t* g, ushort_t* l){
    __builtin_amdgcn_global_load_lds(
        (const __attribute__((address_space(1))) void*)g,
        (__attribute__((address_space(3))) void*)l,
        16, 0, 0);
}

// ---------------- weight transpose + convert (f32 [K][N] -> bf16 [N][K]) ----------------
__global__ __launch_bounds__(256) void transpose_w(const float* __restrict__ in,
                                                   ushort_t* __restrict__ out,
                                                   int K, int N){
    __shared__ ushort_t t[32][33];
    int tx = threadIdx.x & 31, ty = threadIdx.x >> 5;
    int bx = blockIdx.x, by = blockIdx.y;
    #pragma unroll
    for (int r = 0; r < 4; ++r)
        t[ty + r*8][tx] = f2bf(in[(size_t)(by*32 + ty + r*8) * N + bx*32 + tx]);
    __syncthreads();
    #pragma unroll
    for (int r = 0; r < 4; ++r)
        out[(size_t)(bx*32 + ty + r*8) * K + by*32 + tx] = t[tx][ty + r*8];
}

// ---------------- LayerNorm (row = 1024), f32 in -> bf16 out ----------------
__global__ __launch_bounds__(256) void ln_kernel(const float* __restrict__ xin,
                                                 const float* __restrict__ g,
                                                 const float* __restrict__ bia,
                                                 ushort_t* __restrict__ out){
    int row = blockIdx.x;
    int tid = threadIdx.x;
    const float* x = xin + (size_t)row * EMB;
    float4 f = *(const float4*)(x + tid*4);
    float v[4] = {f.x, f.y, f.z, f.w};
    float s = v[0]+v[1]+v[2]+v[3];
    float q = v[0]*v[0]+v[1]*v[1]+v[2]*v[2]+v[3]*v[3];
    #pragma unroll
    for (int o = 32; o > 0; o >>= 1){ s += __shfl_down(s, o); q += __shfl_down(q, o); }
    __shared__ float ss[4], qq[4];
    __shared__ float mu_s, sc_s;
    int wave = tid >> 6, lane = tid & 63;
    if (lane == 0){ ss[wave] = s; qq[wave] = q; }
    __syncthreads();
    if (tid == 0){
        float S = ss[0]+ss[1]+ss[2]+ss[3];
        float Q = qq[0]+qq[1]+qq[2]+qq[3];
        float mu = S * (1.0f/EMB);
        float var = Q * (1.0f/EMB) - mu*mu;
        mu_s = mu; sc_s = rsqrtf(var + 1e-5f);
    }
    __syncthreads();
    float mu = mu_s, sc = sc_s;
    float4 gu = *(const float4*)(g + tid*4);
    float4 bu = *(const float4*)(bia + tid*4);
    ushort4 o4;
    o4.x = f2bf((v[0]-mu)*sc*gu.x + bu.x);
    o4.y = f2bf((v[1]-mu)*sc*gu.y + bu.y);
    o4.z = f2bf((v[2]-mu)*sc*gu.z + bu.z);
    o4.w = f2bf((v[3]-mu)*sc*gu.w + bu.w);
    *(ushort4*)(out + (size_t)row*EMB + tid*4) = o4;
}

// ---------------- GEMM (m97 structure): C[M][N] = epi(A[M][K] @ Bt[N][K]^T) ----------------
// A, Bt bf16; bias/resid f32.
// MODE 0: plain -> bf16 | 1: +bias+resid -> f32 | 2: +bias+GELU -> bf16 | 3: +bias+resid -> f32
template<int MODE>
__global__ __launch_bounds__(256) void gemm_kernel(const ushort_t* __restrict__ A,
                                                   const ushort_t* __restrict__ Bt,
                                                   const float* __restrict__ bias,
                                                   const float* __restrict__ resid,
                                                   void* __restrict__ out,
                                                   int M, int N, int K){
    __shared__ ushort_t As[128*64];   // unpadded: required by global_load_lds lane layout
    __shared__ ushort_t Bs[128*64];
    int tid = threadIdx.x;
    int lane = tid & 63, wave = tid >> 6;
    int quad = lane >> 4, l15 = lane & 15;
    int wm = wave >> 1, wn = wave & 1;
    int m0 = blockIdx.y * 128, n0 = blockIdx.x * 128;

    f32x4 acc[4][4];
    #pragma unroll
    for (int i=0;i<4;i++)
        #pragma unroll
        for (int j=0;j<4;j++) acc[i][j] = (f32x4){0.f,0.f,0.f,0.f};

    int lr = lane >> 3;         // 0..7
    int lc = (lane & 7) * 8;    // 0..56
    const ushort_t* gA = A  + (size_t)(m0 + wave*32 + lr)*K + lc;
    const ushort_t* gB = Bt + (size_t)(n0 + wave*32 + lr)*K + lc;
    ushort_t* lA = &As[(wave*32)*64];
    ushort_t* lB = &Bs[(wave*32)*64];

    for (int k0 = 0; k0 < K; k0 += 64){
        #pragma unroll
        for (int i = 0; i < 4; ++i){
            gload16(gA + (size_t)(i*8)*K + k0, lA + i*8*64);
            gload16(gB + (size_t)(i*8)*K + k0, lB + i*8*64);
        }
        __syncthreads();
        #pragma unroll
        for (int kf = 0; kf < 2; ++kf){
            bf16x8 af[4], bfr[4];
            #pragma unroll
            for (int i=0;i<4;i++) af[i]  = *(const bf16x8*)&As[(wm*64 + i*16 + l15)*64 + kf*32 + quad*8];
            #pragma unroll
            for (int j=0;j<4;j++) bfr[j] = *(const bf16x8*)&Bs[(wn*64 + j*16 + l15)*64 + kf*32 + quad*8];
            #pragma unroll
            for (int i=0;i<4;i++)
                #pragma unroll
                for (int j=0;j<4;j++)
                    acc[i][j] = __builtin_amdgcn_mfma_f32_16x16x32_bf16(af[i], bfr[j], acc[i][j], 0,0,0);
        }
        __syncthreads();
    }

    #pragma unroll
    for (int i=0;i<4;i++){
        int m = m0 + wm*64 + i*16 + quad*4;
        #pragma unroll
        for (int j=0;j<4;j++){
            int n = n0 + wn*64 + j*16 + l15;
            #pragma unroll
            for (int r=0;r<4;r++){
                float v = acc[i][j][r];
                size_t idx = (size_t)(m + r)*N + n;
                if (MODE == 0){
                    ((ushort_t*)out)[idx] = f2bf(v);
                } else if (MODE == 1){
                    v += bias[n] + resid[idx];
                    ((float*)out)[idx] = v;
                } else if (MODE == 2){
                    v += bias[n];
                    v = 0.5f * v * (1.0f + erff(v * 0.70710678118654752f));
                    ((ushort_t*)out)[idx] = f2bf(v);
                } else {
                    v += bias[n] + resid[idx];
                    ((float*)out)[idx] = v;
                }
            }
        }
    }
}

// ---------------- Flash attention (causal), D=64, KV tile = 64, paired q-tiles ----------------
__global__ __launch_bounds__(256) void attn_kernel(const ushort_t* __restrict__ qkv,
                                                   ushort_t* __restrict__ attn_out){
    __shared__ ushort_t Qs[128][72];
    __shared__ ushort_t Ks[64][72];
    __shared__ ushort_t Vts[64][72];   // V transposed + XOR-swizzled: (d,k) -> Vts[d][k ^ ((d>>3&7)<<3)]
    __shared__ ushort_t Ps[128][72];

    int tid = threadIdx.x;
    int lane = tid & 63, wave = tid >> 6;
    int quad = lane >> 4, l15 = lane & 15;
    int pair = blockIdx.x;         // 0..3
    int bh = blockIdx.y;           // 0..127
    int b = bh >> 4, h = bh & 15;
    size_t tb = (size_t)b * SEQ;

    int tr = tid >> 3;             // 0..31
    int tc = (tid & 7) * 8;        // 0..56
    int sw_w = tid & 7;            // = tc>>3, V-write swizzle

    for (int t = 0; t < 2; ++t){
        int qi = t ? (7 - pair) : pair;

        // stage Q tile [128][64]  (barrier provided by first j-iteration's sync)
        #pragma unroll
        for (int p = 0; p < 4; ++p){
            int r = tr + p*32;
            size_t tok = tb + qi*128 + r;
            *(bf16x8*)&Qs[r][tc] = *(const bf16x8*)(qkv + tok*3072 + h*64 + tc);
        }

        f32x4 o_acc[2][4];
        #pragma unroll
        for (int mt=0;mt<2;mt++)
            #pragma unroll
            for (int nt=0;nt<4;nt++) o_acc[mt][nt] = (f32x4){0.f,0.f,0.f,0.f};
        float m_st[2][4], l_st[2][4];
        #pragma unroll
        for (int mt=0;mt<2;mt++)
            #pragma unroll
            for (int r=0;r<4;r++){ m_st[mt][r] = -1e30f; l_st[mt][r] = 0.f; }

        int nj = 2*qi + 2;
        for (int j = 0; j < nj; ++j){
            // stage K tile [64][64] and V transposed+swizzled
            #pragma unroll
            for (int p = 0; p < 2; ++p){
                int r = tr + p*32;
                size_t tok = tb + j*64 + r;
                *(bf16x8*)&Ks[r][tc] = *(const bf16x8*)(qkv + tok*3072 + 1024 + h*64 + tc);
                bf16x8 vv = *(const bf16x8*)(qkv + tok*3072 + 2048 + h*64 + tc);
                int kcol = r ^ (sw_w << 3);
                #pragma unroll
                for (int c = 0; c < 8; ++c) Vts[tc + c][kcol] = (ushort_t)vv[c];
            }
            __syncthreads();

            // S = Q @ K^T
            f32x4 s_acc[2][4];
            #pragma unroll
            for (int mt=0;mt<2;mt++)
                #pragma unroll
                for (int nt=0;nt<4;nt++) s_acc[mt][nt] = (f32x4){0.f,0.f,0.f,0.f};
            #pragma unroll
            for (int kf = 0; kf < 2; ++kf){
                bf16x8 aq[2], bk[4];
                #pragma unroll
                for (int mt=0;mt<2;mt++) aq[mt] = *(const bf16x8*)&Qs[wave*32 + mt*16 + l15][kf*32 + quad*8];
                #pragma unroll
                for (int nt=0;nt<4;nt++) bk[nt] = *(const bf16x8*)&Ks[nt*16 + l15][kf*32 + quad*8];
                #pragma unroll
                for (int mt=0;mt<2;mt++)
                    #pragma unroll
                    for (int nt=0;nt<4;nt++)
                        s_acc[mt][nt] = __builtin_amdgcn_mfma_f32_16x16x32_bf16(aq[mt], bk[nt], s_acc[mt][nt], 0,0,0);
            }

            bool need_mask = (j >= 2*qi);
            #pragma unroll
            for (int mt=0;mt<2;mt++)
                #pragma unroll
                for (int nt=0;nt<4;nt++)
                    #pragma unroll
                    for (int r=0;r<4;r++){
                        float s = s_acc[mt][nt][r] * 0.125f;
                        if (need_mask){
                            int qg = qi*128 + wave*32 + mt*16 + quad*4 + r;
                            int kg = j*64 + nt*16 + l15;
                            if (kg > qg) s = -1e30f;
                        }
                        s_acc[mt][nt][r] = s;
                    }

            // online softmax per q row
            #pragma unroll
            for (int mt=0;mt<2;mt++){
                #pragma unroll
                for (int r=0;r<4;r++){
                    float rm = s_acc[mt][0][r];
                    #pragma unroll
                    for (int nt=1;nt<4;nt++) rm = fmaxf(rm, s_acc[mt][nt][r]);
                    rm = fmaxf(rm, __shfl_xor(rm, 1));
                    rm = fmaxf(rm, __shfl_xor(rm, 2));
                    rm = fmaxf(rm, __shfl_xor(rm, 4));
                    rm = fmaxf(rm, __shfl_xor(rm, 8));
                    float mnew = fmaxf(m_st[mt][r], rm);
                    float alpha = __expf(m_st[mt][r] - mnew);
                    float rsum = 0.f;
                    #pragma unroll
                    for (int nt=0;nt<4;nt++){
                        float p = __expf(s_acc[mt][nt][r] - mnew);
                        s_acc[mt][nt][r] = p;
                        rsum += p;
                    }
                    rsum += __shfl_xor(rsum, 1);
                    rsum += __shfl_xor(rsum, 2);
                    rsum += __shfl_xor(rsum, 4);
                    rsum += __shfl_xor(rsum, 8);
                    l_st[mt][r] = l_st[mt][r]*alpha + rsum;
                    m_st[mt][r] = mnew;
                    #pragma unroll
                    for (int nt=0;nt<4;nt++) o_acc[mt][nt][r] *= alpha;
                }
            }

            // write P (bf16) to LDS (wave-private rows)
            #pragma unroll
            for (int mt=0;mt<2;mt++)
                #pragma unroll
                for (int nt=0;nt<4;nt++)
                    #pragma unroll
                    for (int r=0;r<4;r++)
                        Ps[wave*32 + mt*16 + quad*4 + r][nt*16 + l15] = f2bf(s_acc[mt][nt][r]);

            // O += P @ V   (B-frag from swizzled Vts)
            #pragma unroll
            for (int kf = 0; kf < 2; ++kf){
                bf16x8 ap[2], bv[4];
                #pragma unroll
                for (int mt=0;mt<2;mt++) ap[mt] = *(const bf16x8*)&Ps[wave*32 + mt*16 + l15][kf*32 + quad*8];
                #pragma unroll
                for (int nt=0;nt<4;nt++){
                    int d = nt*16 + l15;
                    int col = (kf*32 + quad*8) ^ (((d >> 3) & 7) << 3);
                    bv[nt] = *(const bf16x8*)&Vts[d][col];
                }
                #pragma unroll
                for (int mt=0;mt<2;mt++)
                    #pragma unroll
                    for (int nt=0;nt<4;nt++)
                        o_acc[mt][nt] = __builtin_amdgcn_mfma_f32_16x16x32_bf16(ap[mt], bv[nt], o_acc[mt][nt], 0,0,0);
            }
            __syncthreads();
        }

        // epilogue: O /= l, store bf16
        #pragma unroll
        for (int mt=0;mt<2;mt++)
            #pragma unroll
            for (int r=0;r<4;r++){
                float inv = 1.0f / l_st[mt][r];
                size_t tok = tb + qi*128 + wave*32 + mt*16 + quad*4 + r;
                #pragma unroll
                for (int nt=0;nt<4;nt++)
                    attn_out[tok*EMB + h*64 + nt*16 + l15] = f2bf(o_acc[mt][nt][r] * inv);
            }
    }
}

extern "C" void kernel_launch(void* const* d_in, const int* in_sizes, int n_in,
                              void* d_out, int out_size, void* d_ws, size_t ws_size,
                              hipStream_t stream){
    const float* x      = (const float*)d_in[0];
    const float* ln1_g  = (const float*)d_in[1];
    const float* ln1_b  = (const float*)d_in[2];
    const float* wq     = (const float*)d_in[3];
    const float* wk     = (const float*)d_in[4];
    const float* wv     = (const float*)d_in[5];
    const float* w_proj = (const float*)d_in[6];
    const float* b_proj = (const float*)d_in[7];
    const float* ln2_g  = (const float*)d_in[8];
    const float* ln2_b  = (const float*)d_in[9];
    const float* w1     = (const float*)d_in[10];
    const float* b1     = (const float*)d_in[11];
    const float* w2     = (const float*)d_in[12];
    const float* b2     = (const float*)d_in[13];
    float* outp = (float*)d_out;

    char* ws = (char*)d_ws;
    size_t off = 0;
    auto alloc = [&](size_t bytes)->char*{ char* p = ws + off; off += (bytes + 255) & ~255ULL; return p; };
    ushort_t* wqkv_t = (ushort_t*)alloc((size_t)3072*1024*2);
    ushort_t* wproj_t= (ushort_t*)alloc((size_t)1024*1024*2);
    ushort_t* w1_t   = (ushort_t*)alloc((size_t)4096*1024*2);
    ushort_t* w2_t   = (ushort_t*)alloc((size_t)1024*4096*2);
    ushort_t* qkv    = (ushort_t*)alloc((size_t)ROWS*3072*2);
    ushort_t* hbuf   = (ushort_t*)alloc((size_t)ROWS*1024*2);
    float*    out32  = (float*)  alloc((size_t)ROWS*1024*4);
    ushort_t* mid    = (ushort_t*)alloc((size_t)ROWS*4096*2);
    ushort_t* h1 = hbuf;
    ushort_t* attn = hbuf;   // h1 dead after qkv GEMM
    ushort_t* h2 = qkv;      // qkv dead after attention

    dim3 blk(256);
    transpose_w<<<dim3(32,32),  blk, 0, stream>>>(wq,     wqkv_t,               1024, 1024);
    transpose_w<<<dim3(32,32),  blk, 0, stream>>>(wk,     wqkv_t + 1024*1024,   1024, 1024);
    transpose_w<<<dim3(32,32),  blk, 0, stream>>>(wv,     wqkv_t + 2*1024*1024, 1024, 1024);
    transpose_w<<<dim3(32,32),  blk, 0, stream>>>(w_proj, wproj_t,              1024, 1024);
    transpose_w<<<dim3(128,32), blk, 0, stream>>>(w1,     w1_t,                 1024, 4096);
    transpose_w<<<dim3(32,128), blk, 0, stream>>>(w2,     w2_t,                 4096, 1024);

    ln_kernel<<<ROWS, blk, 0, stream>>>(x, ln1_g, ln1_b, h1);
    gemm_kernel<0><<<dim3(3072/128, ROWS/128), blk, 0, stream>>>(h1, wqkv_t, nullptr, nullptr, qkv, ROWS, 3072, 1024);
    attn_kernel<<<dim3(4,128), blk, 0, stream>>>(qkv, attn);
    gemm_kernel<1><<<dim3(1024/128, ROWS/128), blk, 0, stream>>>(attn, wproj_t, b_proj, x, out32, ROWS, 1024, 1024);
    ln_kernel<<<ROWS, blk, 0, stream>>>(out32, ln2_g, ln2_b, h2);
    gemm_kernel<2><<<dim3(4096/128, ROWS/128), blk, 0, stream>>>(h2, w1_t, b1, nullptr, mid, ROWS, 4096, 1024);
    gemm_kernel<3><<<dim3(1024/128, ROWS/128), blk, 0, stream>>>(mid, w2_t, b2, out32, outp, ROWS, 1024, 4096);
}

// Round 4
// 541.423 us; speedup vs baseline: 1.1134x; 1.0486x over previous
//
#include <hip/hip_runtime.h>
#include <hip/hip_bf16.h>

#define EMB 1024
#define NH 16
#define HD 64
#define BATCH 8
#define SEQ 1024
#define ROWS (BATCH*SEQ)   // 8192

typedef unsigned short ushort_t;
typedef __attribute__((ext_vector_type(8))) short bf16x8;
typedef __attribute__((ext_vector_type(4))) float f32x4;

__device__ __forceinline__ float bf2f(ushort_t u){
    union { unsigned int i; float f; } v; v.i = ((unsigned int)u) << 16; return v.f;
}
__device__ __forceinline__ ushort_t f2bf(float f){
    unsigned int u = __float_as_uint(f);
    unsigned int r = (u + 0x7FFFu + ((u >> 16) & 1u)) >> 16;
    return (ushort_t)r;
}
__device__ __forceinline__ void gload16(const ushort_t* g, ushort_t* l){
    __builtin_amdgcn_global_load_lds(
        (const __attribute__((address_space(1))) void*)g,
        (__attribute__((address_space(3))) void*)l,
        16, 0, 0);
}
// exact-erf GELU via A&S 7.1.26 (|err| < 1.5e-7)
__device__ __forceinline__ float gelu_f(float v){
    float x = fabsf(v) * 0.70710678118654752f;
    float t = __builtin_amdgcn_rcpf(1.0f + 0.3275911f * x);
    float poly = t*(0.254829592f + t*(-0.284496736f + t*(1.421413741f + t*(-1.453152027f + t*1.061405429f))));
    float erfa = 1.0f - poly * __expf(-x*x);
    float erfv = (v >= 0.f) ? erfa : -erfa;
    return 0.5f * v * (1.0f + erfv);
}

// ---------------- weight transpose + convert (f32 [K][N] -> bf16 [N][K]) ----------------
__global__ __launch_bounds__(256) void transpose_w(const float* __restrict__ in,
                                                   ushort_t* __restrict__ out,
                                                   int K, int N){
    __shared__ ushort_t t[32][33];
    int tx = threadIdx.x & 31, ty = threadIdx.x >> 5;
    int bx = blockIdx.x, by = blockIdx.y;
    #pragma unroll
    for (int r = 0; r < 4; ++r)
        t[ty + r*8][tx] = f2bf(in[(size_t)(by*32 + ty + r*8) * N + bx*32 + tx]);
    __syncthreads();
    #pragma unroll
    for (int r = 0; r < 4; ++r)
        out[(size_t)(bx*32 + ty + r*8) * K + by*32 + tx] = t[tx][ty + r*8];
}

// ---------------- LayerNorm (row = 1024), f32 in -> bf16 out ----------------
__global__ __launch_bounds__(256) void ln_kernel(const float* __restrict__ xin,
                                                 const float* __restrict__ g,
                                                 const float* __restrict__ bia,
                                                 ushort_t* __restrict__ out){
    int row = blockIdx.x;
    int tid = threadIdx.x;
    const float* x = xin + (size_t)row * EMB;
    float4 f = *(const float4*)(x + tid*4);
    float v[4] = {f.x, f.y, f.z, f.w};
    float s = v[0]+v[1]+v[2]+v[3];
    float q = v[0]*v[0]+v[1]*v[1]+v[2]*v[2]+v[3]*v[3];
    #pragma unroll
    for (int o = 32; o > 0; o >>= 1){ s += __shfl_down(s, o); q += __shfl_down(q, o); }
    __shared__ float ss[4], qq[4];
    __shared__ float mu_s, sc_s;
    int wave = tid >> 6, lane = tid & 63;
    if (lane == 0){ ss[wave] = s; qq[wave] = q; }
    __syncthreads();
    if (tid == 0){
        float S = ss[0]+ss[1]+ss[2]+ss[3];
        float Q = qq[0]+qq[1]+qq[2]+qq[3];
        float mu = S * (1.0f/EMB);
        float var = Q * (1.0f/EMB) - mu*mu;
        mu_s = mu; sc_s = rsqrtf(var + 1e-5f);
    }
    __syncthreads();
    float mu = mu_s, sc = sc_s;
    float4 gu = *(const float4*)(g + tid*4);
    float4 bu = *(const float4*)(bia + tid*4);
    ushort4 o4;
    o4.x = f2bf((v[0]-mu)*sc*gu.x + bu.x);
    o4.y = f2bf((v[1]-mu)*sc*gu.y + bu.y);
    o4.z = f2bf((v[2]-mu)*sc*gu.z + bu.z);
    o4.w = f2bf((v[3]-mu)*sc*gu.w + bu.w);
    *(ushort4*)(out + (size_t)row*EMB + tid*4) = o4;
}

// ---------------- GEMM (m97 + XOR-swizzled LDS): C = epi(A[M][K] @ Bt[N][K]^T) ----------------
// LDS chunk c (16B) of row r holds global chunk c ^ (r&7)  -> conflict-free ds_read_b128.
// MODE 0: plain -> bf16 | 1: +bias+resid -> f32 | 2: +bias+GELU -> bf16 | 3: +bias+resid -> f32
template<int MODE>
__global__ __launch_bounds__(256) void gemm_kernel(const ushort_t* __restrict__ A,
                                                   const ushort_t* __restrict__ Bt,
                                                   const float* __restrict__ bias,
                                                   const float* __restrict__ resid,
                                                   void* __restrict__ out,
                                                   int M, int N, int K){
    __shared__ ushort_t As[128*64];   // unpadded: required by global_load_lds lane layout
    __shared__ ushort_t Bs[128*64];
    int tid = threadIdx.x;
    int lane = tid & 63, wave = tid >> 6;
    int quad = lane >> 4, l15 = lane & 15;
    int wm = wave >> 1, wn = wave & 1;
    int m0 = blockIdx.y * 128, n0 = blockIdx.x * 128;

    f32x4 acc[4][4];
    #pragma unroll
    for (int i=0;i<4;i++)
        #pragma unroll
        for (int j=0;j<4;j++) acc[i][j] = (f32x4){0.f,0.f,0.f,0.f};

    int lr  = lane >> 3;        // row within 8-row group
    int lch = lane & 7;         // destination LDS chunk
    // source chunk = lch ^ (row&7) = lch ^ lr (row = wave*32 + i*8 + lr)
    const ushort_t* gA = A  + (size_t)(m0 + wave*32 + lr)*K + (lch ^ lr)*8;
    const ushort_t* gB = Bt + (size_t)(n0 + wave*32 + lr)*K + (lch ^ lr)*8;
    ushort_t* lA = &As[(wave*32)*64];
    ushort_t* lB = &Bs[(wave*32)*64];
    int sx = l15 & 7;           // fragment-read swizzle

    for (int k0 = 0; k0 < K; k0 += 64){
        #pragma unroll
        for (int i = 0; i < 4; ++i){
            gload16(gA + (size_t)(i*8)*K + k0, lA + i*8*64);
            gload16(gB + (size_t)(i*8)*K + k0, lB + i*8*64);
        }
        __syncthreads();
        #pragma unroll
        for (int kf = 0; kf < 2; ++kf){
            int ch = (kf*4 + quad) ^ sx;
            bf16x8 af[4], bfr[4];
            #pragma unroll
            for (int i=0;i<4;i++) af[i]  = *(const bf16x8*)&As[(wm*64 + i*16 + l15)*64 + ch*8];
            #pragma unroll
            for (int j=0;j<4;j++) bfr[j] = *(const bf16x8*)&Bs[(wn*64 + j*16 + l15)*64 + ch*8];
            #pragma unroll
            for (int i=0;i<4;i++)
                #pragma unroll
                for (int j=0;j<4;j++)
                    acc[i][j] = __builtin_amdgcn_mfma_f32_16x16x32_bf16(af[i], bfr[j], acc[i][j], 0,0,0);
        }
        __syncthreads();
    }

    #pragma unroll
    for (int i=0;i<4;i++){
        int m = m0 + wm*64 + i*16 + quad*4;
        #pragma unroll
        for (int j=0;j<4;j++){
            int n = n0 + wn*64 + j*16 + l15;
            #pragma unroll
            for (int r=0;r<4;r++){
                float v = acc[i][j][r];
                size_t idx = (size_t)(m + r)*N + n;
                if (MODE == 0){
                    ((ushort_t*)out)[idx] = f2bf(v);
                } else if (MODE == 1){
                    v += bias[n] + resid[idx];
                    ((float*)out)[idx] = v;
                } else if (MODE == 2){
                    v += bias[n];
                    ((ushort_t*)out)[idx] = f2bf(gelu_f(v));
                } else {
                    v += bias[n] + resid[idx];
                    ((float*)out)[idx] = v;
                }
            }
        }
    }
}

// ---------------- Flash attention (causal), D=64, KV tile = 64, paired q-tiles ----------------
__global__ __launch_bounds__(256) void attn_kernel(const ushort_t* __restrict__ qkv,
                                                   ushort_t* __restrict__ attn_out){
    __shared__ ushort_t Qs[128][72];
    __shared__ ushort_t Ks[64][72];
    __shared__ ushort_t Vts[64][72];   // V transposed + XOR-swizzled: (d,k) -> Vts[d][k ^ ((d>>3&7)<<3)]
    __shared__ ushort_t Ps[128][72];

    int tid = threadIdx.x;
    int lane = tid & 63, wave = tid >> 6;
    int quad = lane >> 4, l15 = lane & 15;
    int pair = blockIdx.x;         // 0..3
    int bh = blockIdx.y;           // 0..127
    int b = bh >> 4, h = bh & 15;
    size_t tb = (size_t)b * SEQ;

    int tr = tid >> 3;             // 0..31
    int tc = (tid & 7) * 8;        // 0..56
    int sw_w = tid & 7;            // V-write swizzle

    for (int t = 0; t < 2; ++t){
        int qi = t ? (7 - pair) : pair;

        #pragma unroll
        for (int p = 0; p < 4; ++p){
            int r = tr + p*32;
            size_t tok = tb + qi*128 + r;
            *(bf16x8*)&Qs[r][tc] = *(const bf16x8*)(qkv + tok*3072 + h*64 + tc);
        }

        f32x4 o_acc[2][4];
        #pragma unroll
        for (int mt=0;mt<2;mt++)
            #pragma unroll
            for (int nt=0;nt<4;nt++) o_acc[mt][nt] = (f32x4){0.f,0.f,0.f,0.f};
        float m_st[2][4], l_st[2][4];
        #pragma unroll
        for (int mt=0;mt<2;mt++)
            #pragma unroll
            for (int r=0;r<4;r++){ m_st[mt][r] = -1e30f; l_st[mt][r] = 0.f; }

        int nj = 2*qi + 2;
        for (int j = 0; j < nj; ++j){
            #pragma unroll
            for (int p = 0; p < 2; ++p){
                int r = tr + p*32;
                size_t tok = tb + j*64 + r;
                *(bf16x8*)&Ks[r][tc] = *(const bf16x8*)(qkv + tok*3072 + 1024 + h*64 + tc);
                bf16x8 vv = *(const bf16x8*)(qkv + tok*3072 + 2048 + h*64 + tc);
                int kcol = r ^ (sw_w << 3);
                #pragma unroll
                for (int c = 0; c < 8; ++c) Vts[tc + c][kcol] = (ushort_t)vv[c];
            }
            __syncthreads();

            f32x4 s_acc[2][4];
            #pragma unroll
            for (int mt=0;mt<2;mt++)
                #pragma unroll
                for (int nt=0;nt<4;nt++) s_acc[mt][nt] = (f32x4){0.f,0.f,0.f,0.f};
            #pragma unroll
            for (int kf = 0; kf < 2; ++kf){
                bf16x8 aq[2], bk[4];
                #pragma unroll
                for (int mt=0;mt<2;mt++) aq[mt] = *(const bf16x8*)&Qs[wave*32 + mt*16 + l15][kf*32 + quad*8];
                #pragma unroll
                for (int nt=0;nt<4;nt++) bk[nt] = *(const bf16x8*)&Ks[nt*16 + l15][kf*32 + quad*8];
                #pragma unroll
                for (int mt=0;mt<2;mt++)
                    #pragma unroll
                    for (int nt=0;nt<4;nt++)
                        s_acc[mt][nt] = __builtin_amdgcn_mfma_f32_16x16x32_bf16(aq[mt], bk[nt], s_acc[mt][nt], 0,0,0);
            }

            bool need_mask = (j >= 2*qi);
            #pragma unroll
            for (int mt=0;mt<2;mt++)
                #pragma unroll
                for (int nt=0;nt<4;nt++)
                    #pragma unroll
                    for (int r=0;r<4;r++){
                        float s = s_acc[mt][nt][r] * 0.125f;
                        if (need_mask){
                            int qg = qi*128 + wave*32 + mt*16 + quad*4 + r;
                            int kg = j*64 + nt*16 + l15;
                            if (kg > qg) s = -1e30f;
                        }
                        s_acc[mt][nt][r] = s;
                    }

            #pragma unroll
            for (int mt=0;mt<2;mt++){
                #pragma unroll
                for (int r=0;r<4;r++){
                    float rm = s_acc[mt][0][r];
                    #pragma unroll
                    for (int nt=1;nt<4;nt++) rm = fmaxf(rm, s_acc[mt][nt][r]);
                    rm = fmaxf(rm, __shfl_xor(rm, 1));
                    rm = fmaxf(rm, __shfl_xor(rm, 2));
                    rm = fmaxf(rm, __shfl_xor(rm, 4));
                    rm = fmaxf(rm, __shfl_xor(rm, 8));
                    float mnew = fmaxf(m_st[mt][r], rm);
                    float alpha = __expf(m_st[mt][r] - mnew);
                    float rsum = 0.f;
                    #pragma unroll
                    for (int nt=0;nt<4;nt++){
                        float p = __expf(s_acc[mt][nt][r] - mnew);
                        s_acc[mt][nt][r] = p;
                        rsum += p;
                    }
                    rsum += __shfl_xor(rsum, 1);
                    rsum += __shfl_xor(rsum, 2);
                    rsum += __shfl_xor(rsum, 4);
                    rsum += __shfl_xor(rsum, 8);
                    l_st[mt][r] = l_st[mt][r]*alpha + rsum;
                    m_st[mt][r] = mnew;
                    #pragma unroll
                    for (int nt=0;nt<4;nt++) o_acc[mt][nt][r] *= alpha;
                }
            }

            #pragma unroll
            for (int mt=0;mt<2;mt++)
                #pragma unroll
                for (int nt=0;nt<4;nt++)
                    #pragma unroll
                    for (int r=0;r<4;r++)
                        Ps[wave*32 + mt*16 + quad*4 + r][nt*16 + l15] = f2bf(s_acc[mt][nt][r]);

            #pragma unroll
            for (int kf = 0; kf < 2; ++kf){
                bf16x8 ap[2], bv[4];
                #pragma unroll
                for (int mt=0;mt<2;mt++) ap[mt] = *(const bf16x8*)&Ps[wave*32 + mt*16 + l15][kf*32 + quad*8];
                #pragma unroll
                for (int nt=0;nt<4;nt++){
                    int d = nt*16 + l15;
                    int col = (kf*32 + quad*8) ^ (((d >> 3) & 7) << 3);
                    bv[nt] = *(const bf16x8*)&Vts[d][col];
                }
                #pragma unroll
                for (int mt=0;mt<2;mt++)
                    #pragma unroll
                    for (int nt=0;nt<4;nt++)
                        o_acc[mt][nt] = __builtin_amdgcn_mfma_f32_16x16x32_bf16(ap[mt], bv[nt], o_acc[mt][nt], 0,0,0);
            }
            __syncthreads();
        }

        #pragma unroll
        for (int mt=0;mt<2;mt++)
            #pragma unroll
            for (int r=0;r<4;r++){
                float inv = 1.0f / l_st[mt][r];
                size_t tok = tb + qi*128 + wave*32 + mt*16 + quad*4 + r;
                #pragma unroll
                for (int nt=0;nt<4;nt++)
                    attn_out[tok*EMB + h*64 + nt*16 + l15] = f2bf(o_acc[mt][nt][r] * inv);
            }
    }
}

extern "C" void kernel_launch(void* const* d_in, const int* in_sizes, int n_in,
                              void* d_out, int out_size, void* d_ws, size_t ws_size,
                              hipStream_t stream){
    const float* x      = (const float*)d_in[0];
    const float* ln1_g  = (const float*)d_in[1];
    const float* ln1_b  = (const float*)d_in[2];
    const float* wq     = (const float*)d_in[3];
    const float* wk     = (const float*)d_in[4];
    const float* wv     = (const float*)d_in[5];
    const float* w_proj = (const float*)d_in[6];
    const float* b_proj = (const float*)d_in[7];
    const float* ln2_g  = (const float*)d_in[8];
    const float* ln2_b  = (const float*)d_in[9];
    const float* w1     = (const float*)d_in[10];
    const float* b1     = (const float*)d_in[11];
    const float* w2     = (const float*)d_in[12];
    const float* b2     = (const float*)d_in[13];
    float* outp = (float*)d_out;

    char* ws = (char*)d_ws;
    size_t off = 0;
    auto alloc = [&](size_t bytes)->char*{ char* p = ws + off; off += (bytes + 255) & ~255ULL; return p; };
    ushort_t* wqkv_t = (ushort_t*)alloc((size_t)3072*1024*2);
    ushort_t* wproj_t= (ushort_t*)alloc((size_t)1024*1024*2);
    ushort_t* w1_t   = (ushort_t*)alloc((size_t)4096*1024*2);
    ushort_t* w2_t   = (ushort_t*)alloc((size_t)1024*4096*2);
    ushort_t* qkv    = (ushort_t*)alloc((size_t)ROWS*3072*2);
    ushort_t* hbuf   = (ushort_t*)alloc((size_t)ROWS*1024*2);
    float*    out32  = (float*)  alloc((size_t)ROWS*1024*4);
    ushort_t* mid    = (ushort_t*)alloc((size_t)ROWS*4096*2);
    ushort_t* h1 = hbuf;
    ushort_t* attn = hbuf;   // h1 dead after qkv GEMM
    ushort_t* h2 = qkv;      // qkv dead after attention

    dim3 blk(256);
    transpose_w<<<dim3(32,32),  blk, 0, stream>>>(wq,     wqkv_t,               1024, 1024);
    transpose_w<<<dim3(32,32),  blk, 0, stream>>>(wk,     wqkv_t + 1024*1024,   1024, 1024);
    transpose_w<<<dim3(32,32),  blk, 0, stream>>>(wv,     wqkv_t + 2*1024*1024, 1024, 1024);
    transpose_w<<<dim3(32,32),  blk, 0, stream>>>(w_proj, wproj_t,              1024, 1024);
    transpose_w<<<dim3(128,32), blk, 0, stream>>>(w1,     w1_t,                 1024, 4096);
    transpose_w<<<dim3(32,128), blk, 0, stream>>>(w2,     w2_t,                 4096, 1024);

    ln_kernel<<<ROWS, blk, 0, stream>>>(x, ln1_g, ln1_b, h1);
    gemm_kernel<0><<<dim3(3072/128, ROWS/128), blk, 0, stream>>>(h1, wqkv_t, nullptr, nullptr, qkv, ROWS, 3072, 1024);
    attn_kernel<<<dim3(4,128), blk, 0, stream>>>(qkv, attn);
    gemm_kernel<1><<<dim3(1024/128, ROWS/128), blk, 0, stream>>>(attn, wproj_t, b_proj, x, out32, ROWS, 1024, 1024);
    ln_kernel<<<ROWS, blk, 0, stream>>>(out32, ln2_g, ln2_b, h2);
    gemm_kernel<2><<<dim3(4096/128, ROWS/128), blk, 0, stream>>>(h2, w1_t, b1, nullptr, mid, ROWS, 4096, 1024);
    gemm_kernel<3><<<dim3(1024/128, ROWS/128), blk, 0, stream>>>(mid, w2_t, b2, out32, outp, ROWS, 1024, 4096);
}